// Round 9
// baseline (131.238 us; speedup 1.0000x reference)
//
#include <hip/hip_runtime.h>
#include <hip/hip_bf16.h>

#define BB 4
#define NN 2048
#define EE 8192
#define RH 150
#define NP 160        // padded hidden dim for MFMA (10 n-tiles / 5 k-steps of 32)
#define HSTR 168      // h1bf LDS row stride (ushorts): mult of 8 (16B align)
#define RSTR 36       // red2 LDS row stride (floats)
#define OH 100

typedef float f4_t   __attribute__((ext_vector_type(4)));
typedef short short8 __attribute__((ext_vector_type(8)));
typedef float f32x4  __attribute__((ext_vector_type(4)));

__device__ __forceinline__ unsigned short f2bf(float f) {
    __hip_bfloat16 h = __float2bfloat16(f);
    return *reinterpret_cast<unsigned short*>(&h);
}

// ---------------------------------------------------------------------------
// scan helper: test one float4 and conditionally record the one-hot row.
// ---------------------------------------------------------------------------
__device__ __forceinline__ void scan_check(const f4_t v, unsigned i4,
                                           int* __restrict__ idx) {
    const float mx = fmaxf(fmaxf(v.x, v.y), fmaxf(v.z, v.w));
    if (mx > 0.5f) {
        const unsigned flat = i4 * 4u;
        const unsigned e = flat & (EE - 1u);
        const unsigned n = (flat >> 13) & (NN - 1u);
        const unsigned b = flat >> 24;
        if (v.x > 0.5f) idx[b * EE + e + 0u] = (int)n;
        if (v.y > 0.5f) idx[b * EE + e + 1u] = (int)n;
        if (v.z > 0.5f) idx[b * EE + e + 2u] = (int)n;
        if (v.w > 0.5f) idx[b * EE + e + 3u] = (int)n;
    }
}

// ---------------------------------------------------------------------------
// Kernel 1: scan both one-hot matrices -> indices; prep bf16-transposed W2
// (w2t[n][k], zero-padded 160x160), padded b2/W3, zero eff_rcv. One dispatch.
// blocks [0,2048) scan S, [2048,4096) scan R.
// Each lane reads TWO consecutive float4 (32 B/lane): second load folds to
// offset:16 on the same address -> 2-deep MLP with zero extra address math.
// Loop left rolled-but-unpragma'd (compiler schedules; manual stride-batches
// regressed in r7/r8).
// ---------------------------------------------------------------------------
__global__ __launch_bounds__(256) void scan_prep_kernel(
    const float* __restrict__ S, const float* __restrict__ R,
    const float* __restrict__ rW2, const float* __restrict__ rb2,
    const float* __restrict__ rW3,
    int* __restrict__ snd_idx, int* __restrict__ rcv_idx,
    unsigned short* __restrict__ w2t, float* __restrict__ b2p,
    float* __restrict__ w3p, float* __restrict__ eff_rcv)
{
    const unsigned gtid = blockIdx.x * 256u + threadIdx.x;

    // ---- prep: bf16-transpose W2 (w2t[n][k] = W2[k][n]), pad b2/W3, zero ----
    if (gtid < NP * NP) {
        const int n = (int)gtid / NP, k = (int)gtid - n * NP;
        w2t[gtid] = (n < RH && k < RH) ? f2bf(rW2[k * RH + n]) : (unsigned short)0;
    }
    if (gtid < NP) {
        b2p[gtid] = (gtid < RH) ? rb2[gtid] : 0.0f;
        w3p[gtid] = (gtid < RH) ? rW3[gtid] : 0.0f;
    }
    if (gtid < BB * NN) eff_rcv[gtid] = 0.0f;

    // ---- scan ----
    const bool second = blockIdx.x >= 2048;
    const f4_t* __restrict__ M4 =
        reinterpret_cast<const f4_t*>(second ? R : S);
    int* __restrict__ idx = second ? rcv_idx : snd_idx;

    // 16,777,216 float4 per matrix = 8,388,608 pairs; 524,288 threads/matrix
    // -> 16 pairs (32 float4) per thread.
    const unsigned stride = 2048u * 256u;
    const unsigned i0 = (blockIdx.x & 2047u) * 256u + threadIdx.x;

    for (unsigned u = 0; u < 16; ++u) {
        const unsigned p = i0 + u * stride;          // pair index
        const f4_t v0 = __builtin_nontemporal_load(M4 + 2u * p);
        const f4_t v1 = __builtin_nontemporal_load(M4 + 2u * p + 1u);
        scan_check(v0, 2u * p, idx);
        scan_check(v1, 2u * p + 1u, idx);
    }
}

// ---------------------------------------------------------------------------
// Edge-MLP body, MFMA version. 512 threads = 8 waves, 64 edges per block.
//  layer 1 (fp32 VALU) -> h1 bf16 in LDS;
//  layer 2: H2[64x160] = H1[64x160] x W2t[160x160] via mfma_f32_16x16x32_bf16;
//  layer 3: relu(C)*W3 epilogue, 2-group LDS reduction, sigmoid.
// ---------------------------------------------------------------------------
__device__ __forceinline__ float edge_mlp_body(
    const float x[7], int t,
    const float* __restrict__ W1, const float* __restrict__ b1,
    const unsigned short* __restrict__ w2t, const float* __restrict__ b2p,
    const float* __restrict__ w3p, const float* __restrict__ b3,
    unsigned short* __restrict__ h1bf, float* __restrict__ red2)
{
    const int e  = t & 63;
    const int w  = t >> 6;               // wave index, uniform

    // ---- layer 1 (fp32) -> h1bf in LDS ----
    for (int j = w; j < NP; j += 8) {
        float v = 0.0f;
        if (j < RH) {
            v = b1[j];
#pragma unroll
            for (int k = 0; k < 7; ++k) v = fmaf(x[k], W1[k * RH + j], v);
            v = fmaxf(v, 0.0f);
        }
        h1bf[e * HSTR + j] = f2bf(v);
    }
    __syncthreads();

    // ---- layer 2 (MFMA) ----
    const int lane = t & 63;
    const int g = w >> 2;                // n-tile group (0: tiles 0-4, 1: 5-9)
    const int m = w & 3;                 // m-tile (edges m*16 .. m*16+15)
    const int c  = lane & 15;
    const int kg = lane >> 4;

    f32x4 acc[5];
#pragma unroll
    for (int nti = 0; nti < 5; ++nti) {
        const float bi = b2p[(g * 5 + nti) * 16 + c];
        acc[nti] = (f32x4){bi, bi, bi, bi};
    }

#pragma unroll
    for (int ks = 0; ks < 5; ++ks) {
        const short8 a = *reinterpret_cast<const short8*>(
            &h1bf[(m * 16 + c) * HSTR + ks * 32 + kg * 8]);
#pragma unroll
        for (int nti = 0; nti < 5; ++nti) {
            const int n = (g * 5 + nti) * 16 + c;
            const short8 bfr = *reinterpret_cast<const short8*>(
                &w2t[n * NP + ks * 32 + kg * 8]);
            acc[nti] = __builtin_amdgcn_mfma_f32_16x16x32_bf16(a, bfr, acc[nti], 0, 0, 0);
        }
    }

    // ---- layer 3 epilogue: relu * W3, per-lane partials ----
    float p0 = 0.0f, p1 = 0.0f, p2 = 0.0f, p3 = 0.0f;
#pragma unroll
    for (int nti = 0; nti < 5; ++nti) {
        const int n = (g * 5 + nti) * 16 + c;
        const float w3v = w3p[n];
        p0 = fmaf(fmaxf(acc[nti][0], 0.0f), w3v, p0);
        p1 = fmaf(fmaxf(acc[nti][1], 0.0f), w3v, p1);
        p2 = fmaf(fmaxf(acc[nti][2], 0.0f), w3v, p2);
        p3 = fmaf(fmaxf(acc[nti][3], 0.0f), w3v, p3);
    }
    {
        const int er = m * 16 + kg * 4;  // C-frag row base for this lane
        red2[(er + 0) * RSTR + g * 16 + c] = p0;
        red2[(er + 1) * RSTR + g * 16 + c] = p1;
        red2[(er + 2) * RSTR + g * 16 + c] = p2;
        red2[(er + 3) * RSTR + g * 16 + c] = p3;
    }
    __syncthreads();

    if (t >= 64) return 0.0f;
    float tot = b3[0];
#pragma unroll
    for (int i = 0; i < 32; ++i) tot += red2[t * RSTR + i];
    return 1.0f / (1.0f + __expf(-tot));
}

// ---------------------------------------------------------------------------
// Kernel 2: edge MLP pass 0 -> atomic scatter-add of effects to receivers.
// ---------------------------------------------------------------------------
__global__ __launch_bounds__(512, 4) void edge0_kernel(
    const float* __restrict__ obj,
    const int* __restrict__ snd_idx, const int* __restrict__ rcv_idx,
    const float* __restrict__ rel,
    const float* __restrict__ W1, const float* __restrict__ b1,
    const unsigned short* __restrict__ w2t, const float* __restrict__ b2p,
    const float* __restrict__ w3p, const float* __restrict__ b3,
    float* __restrict__ eff_rcv)
{
    __shared__ unsigned short h1bf[64 * HSTR];
    __shared__ float red2[64 * RSTR];

    const int t = (int)threadIdx.x;
    const int ebase = (int)blockIdx.x * 64;
    const int eg = ebase + (t & 63);
    const int b = eg >> 13;

    float x[7];
    {
        const int sn = snd_idx[eg];
        const int rn = rcv_idx[eg];
        const float* ps = obj + ((b << 11) + sn) * 3;
        const float* pr = obj + ((b << 11) + rn) * 3;
        x[0] = ps[0]; x[1] = ps[1]; x[2] = ps[2];
        x[3] = pr[0]; x[4] = pr[1]; x[5] = pr[2];
        x[6] = rel[eg];
    }

    const float eff = edge_mlp_body(x, t, W1, b1, w2t, b2p, w3p, b3, h1bf, red2);
    if (t < 64) atomicAdd(&eff_rcv[(b << 11) + rcv_idx[eg]], eff);
}

// ---------------------------------------------------------------------------
// Kernel 3: fused object-MLP prologue + edge MLP pass 1 -> final edge weights.
// ---------------------------------------------------------------------------
__global__ __launch_bounds__(512, 4) void edge1_kernel(
    const float* __restrict__ objects, const float* __restrict__ eff_rcv,
    const int* __restrict__ snd_idx, const int* __restrict__ rcv_idx,
    const float* __restrict__ rel,
    const float* __restrict__ oW1, const float* __restrict__ ob1,
    const float* __restrict__ oW2, const float* __restrict__ ob2,
    const float* __restrict__ W1, const float* __restrict__ b1,
    const unsigned short* __restrict__ w2t, const float* __restrict__ b2p,
    const float* __restrict__ w3p, const float* __restrict__ b3,
    float* __restrict__ out)
{
    __shared__ unsigned short h1bf[64 * HSTR];
    __shared__ float red2[64 * RSTR];
    __shared__ int   nds[128];          // senders [0..64), receivers [64..128)
    __shared__ float onew[128][3];

    const int t = (int)threadIdx.x;
    const int ebase = (int)blockIdx.x * 64;
    const int e = t & 63;
    const int eg = ebase + e;
    const int b = ebase >> 13;          // uniform per block

    if (t < 64)       nds[t] = snd_idx[ebase + t];
    else if (t < 128) nds[t] = rcv_idx[ebase + (t - 64)];
    __syncthreads();

    // object MLP (4 -> 100 relu -> 3) for this block's touched nodes
    if (t < 128) {
        const int node = (b << 11) + nds[t];
        const float x0 = objects[node * 3 + 0];
        const float x1 = objects[node * 3 + 1];
        const float x2 = objects[node * 3 + 2];
        const float x3 = eff_rcv[node];
        float a0 = ob2[0], a1 = ob2[1], a2 = ob2[2];
#pragma unroll 4
        for (int j = 0; j < OH; ++j) {
            float h = ob1[j];
            h = fmaf(x0, oW1[0 * OH + j], h);
            h = fmaf(x1, oW1[1 * OH + j], h);
            h = fmaf(x2, oW1[2 * OH + j], h);
            h = fmaf(x3, oW1[3 * OH + j], h);
            h = fmaxf(h, 0.0f);
            a0 = fmaf(h, oW2[j * 3 + 0], a0);
            a1 = fmaf(h, oW2[j * 3 + 1], a1);
            a2 = fmaf(h, oW2[j * 3 + 2], a2);
        }
        onew[t][0] = a0; onew[t][1] = a1; onew[t][2] = a2;
    }
    __syncthreads();

    float x[7];
    x[0] = onew[e][0];      x[1] = onew[e][1];      x[2] = onew[e][2];
    x[3] = onew[64 + e][0]; x[4] = onew[64 + e][1]; x[5] = onew[64 + e][2];
    x[6] = rel[eg];

    const float eff = edge_mlp_body(x, t, W1, b1, w2t, b2p, w3p, b3, h1bf, red2);
    if (t < 64) out[eg] = eff;
}

// ---------------------------------------------------------------------------
extern "C" void kernel_launch(void* const* d_in, const int* in_sizes, int n_in,
                              void* d_out, int out_size, void* d_ws, size_t ws_size,
                              hipStream_t stream) {
    (void)in_sizes; (void)n_in; (void)out_size; (void)ws_size;

    const float* objects = (const float*)d_in[0];
    const float* S       = (const float*)d_in[1];
    const float* R       = (const float*)d_in[2];
    const float* rel     = (const float*)d_in[3];
    const float* rW1     = (const float*)d_in[4];
    const float* rb1     = (const float*)d_in[5];
    const float* rW2     = (const float*)d_in[6];
    const float* rb2     = (const float*)d_in[7];
    const float* rW3     = (const float*)d_in[8];
    const float* rb3     = (const float*)d_in[9];
    const float* oW1     = (const float*)d_in[10];
    const float* ob1     = (const float*)d_in[11];
    const float* oW2     = (const float*)d_in[12];
    const float* ob2     = (const float*)d_in[13];

    char* ws = (char*)d_ws;
    int*            snd_idx = (int*)(ws + 0);               // 128 KiB
    int*            rcv_idx = (int*)(ws + (128 << 10));     // 128 KiB
    float*          eff_rcv = (float*)(ws + (256 << 10));   //  32 KiB
    unsigned short* w2t     = (unsigned short*)(ws + (288 << 10)); // 50 KiB
    float*          b2p     = (float*)(ws + (344 << 10));   //  640 B
    float*          w3p     = (float*)(ws + (345 << 10));   //  640 B

    // 1) scan one-hot matrices + prep bf16 weights + zero eff_rcv (HBM-bound)
    scan_prep_kernel<<<4096, 256, 0, stream>>>(
        S, R, rW2, rb2, rW3, snd_idx, rcv_idx, w2t, b2p, w3p, eff_rcv);

    // 2) edge MLP pass 0 (MFMA layer 2) -> scatter-add effects
    edge0_kernel<<<(BB * EE) / 64, 512, 0, stream>>>(
        objects, snd_idx, rcv_idx, rel, rW1, rb1, w2t, b2p, w3p, rb3, eff_rcv);

    // 3) fused object MLP + final relational pass (MFMA) -> edge weights
    edge1_kernel<<<(BB * EE) / 64, 512, 0, stream>>>(
        objects, eff_rcv, snd_idx, rcv_idx, rel, oW1, ob1, oW2, ob2,
        rW1, rb1, w2t, b2p, w3p, rb3, (float*)d_out);
}

// Round 10
// 119.156 us; speedup vs baseline: 1.1014x; 1.1014x over previous
//
#include <hip/hip_runtime.h>
#include <hip/hip_bf16.h>

#define BB 4
#define NN 2048
#define EE 8192
#define RH 150
#define NP 160        // padded hidden dim for MFMA (10 n-tiles / 5 k-steps of 32)
#define HSTR 168      // h1bf LDS row stride (ushorts): mult of 8 (16B align)
#define RSTR 36       // red2 LDS row stride (floats)
#define OH 100

typedef float f4_t   __attribute__((ext_vector_type(4)));
typedef short short8 __attribute__((ext_vector_type(8)));
typedef float f32x4  __attribute__((ext_vector_type(4)));

__device__ __forceinline__ unsigned short f2bf(float f) {
    __hip_bfloat16 h = __float2bfloat16(f);
    return *reinterpret_cast<unsigned short*>(&h);
}

// ---------------------------------------------------------------------------
// scan helper: test one float4 and conditionally record the one-hot row.
// ---------------------------------------------------------------------------
__device__ __forceinline__ void scan_check(const f4_t v, unsigned i4,
                                           int* __restrict__ idx) {
    const float mx = fmaxf(fmaxf(v.x, v.y), fmaxf(v.z, v.w));
    if (mx > 0.5f) {
        const unsigned flat = i4 * 4u;
        const unsigned e = flat & (EE - 1u);
        const unsigned n = (flat >> 13) & (NN - 1u);
        const unsigned b = flat >> 24;
        if (v.x > 0.5f) idx[b * EE + e + 0u] = (int)n;
        if (v.y > 0.5f) idx[b * EE + e + 1u] = (int)n;
        if (v.z > 0.5f) idx[b * EE + e + 2u] = (int)n;
        if (v.w > 0.5f) idx[b * EE + e + 3u] = (int)n;
    }
}

// ---------------------------------------------------------------------------
// Kernel 1: scan both one-hot matrices -> indices; prep bf16-transposed W2
// (w2t[n][k], zero-padded 160x160), padded b2/W3, zero eff_rcv. One dispatch.
// blocks [0,2048) scan S, [2048,4096) scan R.
// Block-contiguous chunking: each block streams one contiguous 128 KB chunk
// (32 iters x 4 KB) -> long sequential DRAM runs per block, vs the 8 MB
// grid-stride jumps of r6. Per-lane pattern (16 B contiguous per wave-instr)
// and instruction schedule identical to r6; only index math differs.
// (Manual ILP variants r7/r8/r9 all regressed - compiler schedule wins.)
// ---------------------------------------------------------------------------
__global__ __launch_bounds__(256) void scan_prep_kernel(
    const float* __restrict__ S, const float* __restrict__ R,
    const float* __restrict__ rW2, const float* __restrict__ rb2,
    const float* __restrict__ rW3,
    int* __restrict__ snd_idx, int* __restrict__ rcv_idx,
    unsigned short* __restrict__ w2t, float* __restrict__ b2p,
    float* __restrict__ w3p, float* __restrict__ eff_rcv)
{
    const unsigned gtid = blockIdx.x * 256u + threadIdx.x;

    // ---- prep: bf16-transpose W2 (w2t[n][k] = W2[k][n]), pad b2/W3, zero ----
    if (gtid < NP * NP) {
        const int n = (int)gtid / NP, k = (int)gtid - n * NP;
        w2t[gtid] = (n < RH && k < RH) ? f2bf(rW2[k * RH + n]) : (unsigned short)0;
    }
    if (gtid < NP) {
        b2p[gtid] = (gtid < RH) ? rb2[gtid] : 0.0f;
        w3p[gtid] = (gtid < RH) ? rW3[gtid] : 0.0f;
    }
    if (gtid < BB * NN) eff_rcv[gtid] = 0.0f;

    // ---- scan ----
    const bool second = blockIdx.x >= 2048;
    const f4_t* __restrict__ M4 =
        reinterpret_cast<const f4_t*>(second ? R : S);
    int* __restrict__ idx = second ? rcv_idx : snd_idx;

    // 16,777,216 float4 per matrix / 2048 blocks = 8192 float4 (128 KB) per
    // block, contiguous; 32 iterations of 256 float4 (4 KB).
    const unsigned base = (blockIdx.x & 2047u) * 8192u;
    for (unsigned u = 0; u < 32; ++u) {
        const unsigned i4 = base + u * 256u + threadIdx.x;
        const f4_t v = __builtin_nontemporal_load(M4 + i4);
        scan_check(v, i4, idx);
    }
}

// ---------------------------------------------------------------------------
// Edge-MLP body, MFMA version. 512 threads = 8 waves, 64 edges per block.
//  layer 1 (fp32 VALU) -> h1 bf16 in LDS;
//  layer 2: H2[64x160] = H1[64x160] x W2t[160x160] via mfma_f32_16x16x32_bf16;
//  layer 3: relu(C)*W3 epilogue, 2-group LDS reduction, sigmoid.
// ---------------------------------------------------------------------------
__device__ __forceinline__ float edge_mlp_body(
    const float x[7], int t,
    const float* __restrict__ W1, const float* __restrict__ b1,
    const unsigned short* __restrict__ w2t, const float* __restrict__ b2p,
    const float* __restrict__ w3p, const float* __restrict__ b3,
    unsigned short* __restrict__ h1bf, float* __restrict__ red2)
{
    const int e  = t & 63;
    const int w  = t >> 6;               // wave index, uniform

    // ---- layer 1 (fp32) -> h1bf in LDS ----
    for (int j = w; j < NP; j += 8) {
        float v = 0.0f;
        if (j < RH) {
            v = b1[j];
#pragma unroll
            for (int k = 0; k < 7; ++k) v = fmaf(x[k], W1[k * RH + j], v);
            v = fmaxf(v, 0.0f);
        }
        h1bf[e * HSTR + j] = f2bf(v);
    }
    __syncthreads();

    // ---- layer 2 (MFMA) ----
    const int lane = t & 63;
    const int g = w >> 2;                // n-tile group (0: tiles 0-4, 1: 5-9)
    const int m = w & 3;                 // m-tile (edges m*16 .. m*16+15)
    const int c  = lane & 15;
    const int kg = lane >> 4;

    f32x4 acc[5];
#pragma unroll
    for (int nti = 0; nti < 5; ++nti) {
        const float bi = b2p[(g * 5 + nti) * 16 + c];
        acc[nti] = (f32x4){bi, bi, bi, bi};
    }

#pragma unroll
    for (int ks = 0; ks < 5; ++ks) {
        const short8 a = *reinterpret_cast<const short8*>(
            &h1bf[(m * 16 + c) * HSTR + ks * 32 + kg * 8]);
#pragma unroll
        for (int nti = 0; nti < 5; ++nti) {
            const int n = (g * 5 + nti) * 16 + c;
            const short8 bfr = *reinterpret_cast<const short8*>(
                &w2t[n * NP + ks * 32 + kg * 8]);
            acc[nti] = __builtin_amdgcn_mfma_f32_16x16x32_bf16(a, bfr, acc[nti], 0, 0, 0);
        }
    }

    // ---- layer 3 epilogue: relu * W3, per-lane partials ----
    float p0 = 0.0f, p1 = 0.0f, p2 = 0.0f, p3 = 0.0f;
#pragma unroll
    for (int nti = 0; nti < 5; ++nti) {
        const int n = (g * 5 + nti) * 16 + c;
        const float w3v = w3p[n];
        p0 = fmaf(fmaxf(acc[nti][0], 0.0f), w3v, p0);
        p1 = fmaf(fmaxf(acc[nti][1], 0.0f), w3v, p1);
        p2 = fmaf(fmaxf(acc[nti][2], 0.0f), w3v, p2);
        p3 = fmaf(fmaxf(acc[nti][3], 0.0f), w3v, p3);
    }
    {
        const int er = m * 16 + kg * 4;  // C-frag row base for this lane
        red2[(er + 0) * RSTR + g * 16 + c] = p0;
        red2[(er + 1) * RSTR + g * 16 + c] = p1;
        red2[(er + 2) * RSTR + g * 16 + c] = p2;
        red2[(er + 3) * RSTR + g * 16 + c] = p3;
    }
    __syncthreads();

    if (t >= 64) return 0.0f;
    float tot = b3[0];
#pragma unroll
    for (int i = 0; i < 32; ++i) tot += red2[t * RSTR + i];
    return 1.0f / (1.0f + __expf(-tot));
}

// ---------------------------------------------------------------------------
// Kernel 2: edge MLP pass 0 -> atomic scatter-add of effects to receivers.
// ---------------------------------------------------------------------------
__global__ __launch_bounds__(512, 4) void edge0_kernel(
    const float* __restrict__ obj,
    const int* __restrict__ snd_idx, const int* __restrict__ rcv_idx,
    const float* __restrict__ rel,
    const float* __restrict__ W1, const float* __restrict__ b1,
    const unsigned short* __restrict__ w2t, const float* __restrict__ b2p,
    const float* __restrict__ w3p, const float* __restrict__ b3,
    float* __restrict__ eff_rcv)
{
    __shared__ unsigned short h1bf[64 * HSTR];
    __shared__ float red2[64 * RSTR];

    const int t = (int)threadIdx.x;
    const int ebase = (int)blockIdx.x * 64;
    const int eg = ebase + (t & 63);
    const int b = eg >> 13;

    float x[7];
    {
        const int sn = snd_idx[eg];
        const int rn = rcv_idx[eg];
        const float* ps = obj + ((b << 11) + sn) * 3;
        const float* pr = obj + ((b << 11) + rn) * 3;
        x[0] = ps[0]; x[1] = ps[1]; x[2] = ps[2];
        x[3] = pr[0]; x[4] = pr[1]; x[5] = pr[2];
        x[6] = rel[eg];
    }

    const float eff = edge_mlp_body(x, t, W1, b1, w2t, b2p, w3p, b3, h1bf, red2);
    if (t < 64) atomicAdd(&eff_rcv[(b << 11) + rcv_idx[eg]], eff);
}

// ---------------------------------------------------------------------------
// Kernel 3: fused object-MLP prologue + edge MLP pass 1 -> final edge weights.
// ---------------------------------------------------------------------------
__global__ __launch_bounds__(512, 4) void edge1_kernel(
    const float* __restrict__ objects, const float* __restrict__ eff_rcv,
    const int* __restrict__ snd_idx, const int* __restrict__ rcv_idx,
    const float* __restrict__ rel,
    const float* __restrict__ oW1, const float* __restrict__ ob1,
    const float* __restrict__ oW2, const float* __restrict__ ob2,
    const float* __restrict__ W1, const float* __restrict__ b1,
    const unsigned short* __restrict__ w2t, const float* __restrict__ b2p,
    const float* __restrict__ w3p, const float* __restrict__ b3,
    float* __restrict__ out)
{
    __shared__ unsigned short h1bf[64 * HSTR];
    __shared__ float red2[64 * RSTR];
    __shared__ int   nds[128];          // senders [0..64), receivers [64..128)
    __shared__ float onew[128][3];

    const int t = (int)threadIdx.x;
    const int ebase = (int)blockIdx.x * 64;
    const int e = t & 63;
    const int eg = ebase + e;
    const int b = ebase >> 13;          // uniform per block

    if (t < 64)       nds[t] = snd_idx[ebase + t];
    else if (t < 128) nds[t] = rcv_idx[ebase + (t - 64)];
    __syncthreads();

    // object MLP (4 -> 100 relu -> 3) for this block's touched nodes
    if (t < 128) {
        const int node = (b << 11) + nds[t];
        const float x0 = objects[node * 3 + 0];
        const float x1 = objects[node * 3 + 1];
        const float x2 = objects[node * 3 + 2];
        const float x3 = eff_rcv[node];
        float a0 = ob2[0], a1 = ob2[1], a2 = ob2[2];
#pragma unroll 4
        for (int j = 0; j < OH; ++j) {
            float h = ob1[j];
            h = fmaf(x0, oW1[0 * OH + j], h);
            h = fmaf(x1, oW1[1 * OH + j], h);
            h = fmaf(x2, oW1[2 * OH + j], h);
            h = fmaf(x3, oW1[3 * OH + j], h);
            h = fmaxf(h, 0.0f);
            a0 = fmaf(h, oW2[j * 3 + 0], a0);
            a1 = fmaf(h, oW2[j * 3 + 1], a1);
            a2 = fmaf(h, oW2[j * 3 + 2], a2);
        }
        onew[t][0] = a0; onew[t][1] = a1; onew[t][2] = a2;
    }
    __syncthreads();

    float x[7];
    x[0] = onew[e][0];      x[1] = onew[e][1];      x[2] = onew[e][2];
    x[3] = onew[64 + e][0]; x[4] = onew[64 + e][1]; x[5] = onew[64 + e][2];
    x[6] = rel[eg];

    const float eff = edge_mlp_body(x, t, W1, b1, w2t, b2p, w3p, b3, h1bf, red2);
    if (t < 64) out[eg] = eff;
}

// ---------------------------------------------------------------------------
extern "C" void kernel_launch(void* const* d_in, const int* in_sizes, int n_in,
                              void* d_out, int out_size, void* d_ws, size_t ws_size,
                              hipStream_t stream) {
    (void)in_sizes; (void)n_in; (void)out_size; (void)ws_size;

    const float* objects = (const float*)d_in[0];
    const float* S       = (const float*)d_in[1];
    const float* R       = (const float*)d_in[2];
    const float* rel     = (const float*)d_in[3];
    const float* rW1     = (const float*)d_in[4];
    const float* rb1     = (const float*)d_in[5];
    const float* rW2     = (const float*)d_in[6];
    const float* rb2     = (const float*)d_in[7];
    const float* rW3     = (const float*)d_in[8];
    const float* rb3     = (const float*)d_in[9];
    const float* oW1     = (const float*)d_in[10];
    const float* ob1     = (const float*)d_in[11];
    const float* oW2     = (const float*)d_in[12];
    const float* ob2     = (const float*)d_in[13];

    char* ws = (char*)d_ws;
    int*            snd_idx = (int*)(ws + 0);               // 128 KiB
    int*            rcv_idx = (int*)(ws + (128 << 10));     // 128 KiB
    float*          eff_rcv = (float*)(ws + (256 << 10));   //  32 KiB
    unsigned short* w2t     = (unsigned short*)(ws + (288 << 10)); // 50 KiB
    float*          b2p     = (float*)(ws + (344 << 10));   //  640 B
    float*          w3p     = (float*)(ws + (345 << 10));   //  640 B

    // 1) scan one-hot matrices + prep bf16 weights + zero eff_rcv (HBM-bound)
    scan_prep_kernel<<<4096, 256, 0, stream>>>(
        S, R, rW2, rb2, rW3, snd_idx, rcv_idx, w2t, b2p, w3p, eff_rcv);

    // 2) edge MLP pass 0 (MFMA layer 2) -> scatter-add effects
    edge0_kernel<<<(BB * EE) / 64, 512, 0, stream>>>(
        objects, snd_idx, rcv_idx, rel, rW1, rb1, w2t, b2p, w3p, rb3, eff_rcv);

    // 3) fused object MLP + final relational pass (MFMA) -> edge weights
    edge1_kernel<<<(BB * EE) / 64, 512, 0, stream>>>(
        objects, eff_rcv, snd_idx, rcv_idx, rel, oW1, ob1, oW2, ob2,
        rW1, rb1, w2t, b2p, w3p, rb3, (float*)d_out);
}

// Round 11
// 113.793 us; speedup vs baseline: 1.1533x; 1.0471x over previous
//
#include <hip/hip_runtime.h>
#include <hip/hip_bf16.h>

#define BB 4
#define NN 2048
#define EE 8192
#define RH 150
#define NP 160        // padded hidden dim for MFMA (10 n-tiles / 5 k-steps of 32)
#define HSTR 168      // h1bf LDS row stride (ushorts): mult of 8 (16B align)
#define RSTR 36       // red2 LDS row stride (floats)
#define OH 100

typedef float f4_t   __attribute__((ext_vector_type(4)));
typedef short short8 __attribute__((ext_vector_type(8)));
typedef float f32x4  __attribute__((ext_vector_type(4)));

__device__ __forceinline__ unsigned short f2bf(float f) {
    __hip_bfloat16 h = __float2bfloat16(f);
    return *reinterpret_cast<unsigned short*>(&h);
}

// ---------------------------------------------------------------------------
// Kernel 1: scan both one-hot matrices -> indices; prep bf16-transposed W2
// (w2t[n][k], zero-padded 160x160), padded b2/W3, zero eff_rcv. One dispatch.
// blocks [0,2048) scan S, [2048,4096) scan R. Non-temporal float4 streaming.
// NOTE: the simple rolled grid-stride loop is the WINNER over every manual
// variant tried (16-deep straight-line r7: +30us, 4-group r8: +10us,
// paired-32B r9: +17us, block-contiguous r10: +5us). Compiler schedule wins;
// do not add manual ILP here.
// ---------------------------------------------------------------------------
__global__ __launch_bounds__(256) void scan_prep_kernel(
    const float* __restrict__ S, const float* __restrict__ R,
    const float* __restrict__ rW2, const float* __restrict__ rb2,
    const float* __restrict__ rW3,
    int* __restrict__ snd_idx, int* __restrict__ rcv_idx,
    unsigned short* __restrict__ w2t, float* __restrict__ b2p,
    float* __restrict__ w3p, float* __restrict__ eff_rcv)
{
    const unsigned gtid = blockIdx.x * 256u + threadIdx.x;

    // ---- prep: bf16-transpose W2 (w2t[n][k] = W2[k][n]), pad b2/W3, zero ----
    if (gtid < NP * NP) {
        const int n = (int)gtid / NP, k = (int)gtid - n * NP;
        w2t[gtid] = (n < RH && k < RH) ? f2bf(rW2[k * RH + n]) : (unsigned short)0;
    }
    if (gtid < NP) {
        b2p[gtid] = (gtid < RH) ? rb2[gtid] : 0.0f;
        w3p[gtid] = (gtid < RH) ? rW3[gtid] : 0.0f;
    }
    if (gtid < BB * NN) eff_rcv[gtid] = 0.0f;

    // ---- scan ----
    const bool second = blockIdx.x >= 2048;
    const f4_t* __restrict__ M4 =
        reinterpret_cast<const f4_t*>(second ? R : S);
    int* __restrict__ idx = second ? rcv_idx : snd_idx;

    const unsigned total4 = (unsigned)BB * NN * EE / 4u;  // 16,777,216
    unsigned i = (blockIdx.x & 2047u) * 256u + threadIdx.x;
    const unsigned stride = 2048u * 256u;
    for (; i < total4; i += stride) {
        const f4_t v = __builtin_nontemporal_load(M4 + i);
        if (v.x > 0.5f || v.y > 0.5f || v.z > 0.5f || v.w > 0.5f) {
            const unsigned flat = i * 4u;
            const unsigned e = flat & (EE - 1u);
            const unsigned n = (flat >> 13) & (NN - 1u);
            const unsigned b = flat >> 24;
            if (v.x > 0.5f) idx[b * EE + e + 0u] = (int)n;
            if (v.y > 0.5f) idx[b * EE + e + 1u] = (int)n;
            if (v.z > 0.5f) idx[b * EE + e + 2u] = (int)n;
            if (v.w > 0.5f) idx[b * EE + e + 3u] = (int)n;
        }
    }
}

// ---------------------------------------------------------------------------
// Edge-MLP body, MFMA version. 512 threads = 8 waves, 64 edges per block.
//  layer 1 (fp32 VALU) -> h1 bf16 in LDS;
//  layer 2: H2[64x160] = H1[64x160] x W2t[160x160] via mfma_f32_16x16x32_bf16;
//  layer 3: relu(C)*W3 epilogue, 2-group LDS reduction, sigmoid.
// ---------------------------------------------------------------------------
__device__ __forceinline__ float edge_mlp_body(
    const float x[7], int t,
    const float* __restrict__ W1, const float* __restrict__ b1,
    const unsigned short* __restrict__ w2t, const float* __restrict__ b2p,
    const float* __restrict__ w3p, const float* __restrict__ b3,
    unsigned short* __restrict__ h1bf, float* __restrict__ red2)
{
    const int e  = t & 63;
    const int w  = t >> 6;               // wave index, uniform

    // ---- layer 1 (fp32) -> h1bf in LDS ----
    for (int j = w; j < NP; j += 8) {
        float v = 0.0f;
        if (j < RH) {
            v = b1[j];
#pragma unroll
            for (int k = 0; k < 7; ++k) v = fmaf(x[k], W1[k * RH + j], v);
            v = fmaxf(v, 0.0f);
        }
        h1bf[e * HSTR + j] = f2bf(v);
    }
    __syncthreads();

    // ---- layer 2 (MFMA) ----
    const int lane = t & 63;
    const int g = w >> 2;                // n-tile group (0: tiles 0-4, 1: 5-9)
    const int m = w & 3;                 // m-tile (edges m*16 .. m*16+15)
    const int c  = lane & 15;
    const int kg = lane >> 4;

    f32x4 acc[5];
#pragma unroll
    for (int nti = 0; nti < 5; ++nti) {
        const float bi = b2p[(g * 5 + nti) * 16 + c];
        acc[nti] = (f32x4){bi, bi, bi, bi};
    }

#pragma unroll
    for (int ks = 0; ks < 5; ++ks) {
        const short8 a = *reinterpret_cast<const short8*>(
            &h1bf[(m * 16 + c) * HSTR + ks * 32 + kg * 8]);
#pragma unroll
        for (int nti = 0; nti < 5; ++nti) {
            const int n = (g * 5 + nti) * 16 + c;
            const short8 bfr = *reinterpret_cast<const short8*>(
                &w2t[n * NP + ks * 32 + kg * 8]);
            acc[nti] = __builtin_amdgcn_mfma_f32_16x16x32_bf16(a, bfr, acc[nti], 0, 0, 0);
        }
    }

    // ---- layer 3 epilogue: relu * W3, per-lane partials ----
    float p0 = 0.0f, p1 = 0.0f, p2 = 0.0f, p3 = 0.0f;
#pragma unroll
    for (int nti = 0; nti < 5; ++nti) {
        const int n = (g * 5 + nti) * 16 + c;
        const float w3v = w3p[n];
        p0 = fmaf(fmaxf(acc[nti][0], 0.0f), w3v, p0);
        p1 = fmaf(fmaxf(acc[nti][1], 0.0f), w3v, p1);
        p2 = fmaf(fmaxf(acc[nti][2], 0.0f), w3v, p2);
        p3 = fmaf(fmaxf(acc[nti][3], 0.0f), w3v, p3);
    }
    {
        const int er = m * 16 + kg * 4;  // C-frag row base for this lane
        red2[(er + 0) * RSTR + g * 16 + c] = p0;
        red2[(er + 1) * RSTR + g * 16 + c] = p1;
        red2[(er + 2) * RSTR + g * 16 + c] = p2;
        red2[(er + 3) * RSTR + g * 16 + c] = p3;
    }
    __syncthreads();

    if (t >= 64) return 0.0f;
    float tot = b3[0];
#pragma unroll
    for (int i = 0; i < 32; ++i) tot += red2[t * RSTR + i];
    return 1.0f / (1.0f + __expf(-tot));
}

// ---------------------------------------------------------------------------
// Kernel 2: edge MLP pass 0 -> atomic scatter-add of effects to receivers.
// ---------------------------------------------------------------------------
__global__ __launch_bounds__(512, 4) void edge0_kernel(
    const float* __restrict__ obj,
    const int* __restrict__ snd_idx, const int* __restrict__ rcv_idx,
    const float* __restrict__ rel,
    const float* __restrict__ W1, const float* __restrict__ b1,
    const unsigned short* __restrict__ w2t, const float* __restrict__ b2p,
    const float* __restrict__ w3p, const float* __restrict__ b3,
    float* __restrict__ eff_rcv)
{
    __shared__ unsigned short h1bf[64 * HSTR];
    __shared__ float red2[64 * RSTR];

    const int t = (int)threadIdx.x;
    const int ebase = (int)blockIdx.x * 64;
    const int eg = ebase + (t & 63);
    const int b = eg >> 13;

    float x[7];
    {
        const int sn = snd_idx[eg];
        const int rn = rcv_idx[eg];
        const float* ps = obj + ((b << 11) + sn) * 3;
        const float* pr = obj + ((b << 11) + rn) * 3;
        x[0] = ps[0]; x[1] = ps[1]; x[2] = ps[2];
        x[3] = pr[0]; x[4] = pr[1]; x[5] = pr[2];
        x[6] = rel[eg];
    }

    const float eff = edge_mlp_body(x, t, W1, b1, w2t, b2p, w3p, b3, h1bf, red2);
    if (t < 64) atomicAdd(&eff_rcv[(b << 11) + rcv_idx[eg]], eff);
}

// ---------------------------------------------------------------------------
// Kernel 3: fused object-MLP prologue + edge MLP pass 1 -> final edge weights.
// ---------------------------------------------------------------------------
__global__ __launch_bounds__(512, 4) void edge1_kernel(
    const float* __restrict__ objects, const float* __restrict__ eff_rcv,
    const int* __restrict__ snd_idx, const int* __restrict__ rcv_idx,
    const float* __restrict__ rel,
    const float* __restrict__ oW1, const float* __restrict__ ob1,
    const float* __restrict__ oW2, const float* __restrict__ ob2,
    const float* __restrict__ W1, const float* __restrict__ b1,
    const unsigned short* __restrict__ w2t, const float* __restrict__ b2p,
    const float* __restrict__ w3p, const float* __restrict__ b3,
    float* __restrict__ out)
{
    __shared__ unsigned short h1bf[64 * HSTR];
    __shared__ float red2[64 * RSTR];
    __shared__ int   nds[128];          // senders [0..64), receivers [64..128)
    __shared__ float onew[128][3];

    const int t = (int)threadIdx.x;
    const int ebase = (int)blockIdx.x * 64;
    const int e = t & 63;
    const int eg = ebase + e;
    const int b = ebase >> 13;          // uniform per block

    if (t < 64)       nds[t] = snd_idx[ebase + t];
    else if (t < 128) nds[t] = rcv_idx[ebase + (t - 64)];
    __syncthreads();

    // object MLP (4 -> 100 relu -> 3) for this block's touched nodes
    if (t < 128) {
        const int node = (b << 11) + nds[t];
        const float x0 = objects[node * 3 + 0];
        const float x1 = objects[node * 3 + 1];
        const float x2 = objects[node * 3 + 2];
        const float x3 = eff_rcv[node];
        float a0 = ob2[0], a1 = ob2[1], a2 = ob2[2];
#pragma unroll 4
        for (int j = 0; j < OH; ++j) {
            float h = ob1[j];
            h = fmaf(x0, oW1[0 * OH + j], h);
            h = fmaf(x1, oW1[1 * OH + j], h);
            h = fmaf(x2, oW1[2 * OH + j], h);
            h = fmaf(x3, oW1[3 * OH + j], h);
            h = fmaxf(h, 0.0f);
            a0 = fmaf(h, oW2[j * 3 + 0], a0);
            a1 = fmaf(h, oW2[j * 3 + 1], a1);
            a2 = fmaf(h, oW2[j * 3 + 2], a2);
        }
        onew[t][0] = a0; onew[t][1] = a1; onew[t][2] = a2;
    }
    __syncthreads();

    float x[7];
    x[0] = onew[e][0];      x[1] = onew[e][1];      x[2] = onew[e][2];
    x[3] = onew[64 + e][0]; x[4] = onew[64 + e][1]; x[5] = onew[64 + e][2];
    x[6] = rel[eg];

    const float eff = edge_mlp_body(x, t, W1, b1, w2t, b2p, w3p, b3, h1bf, red2);
    if (t < 64) out[eg] = eff;
}

// ---------------------------------------------------------------------------
extern "C" void kernel_launch(void* const* d_in, const int* in_sizes, int n_in,
                              void* d_out, int out_size, void* d_ws, size_t ws_size,
                              hipStream_t stream) {
    (void)in_sizes; (void)n_in; (void)out_size; (void)ws_size;

    const float* objects = (const float*)d_in[0];
    const float* S       = (const float*)d_in[1];
    const float* R       = (const float*)d_in[2];
    const float* rel     = (const float*)d_in[3];
    const float* rW1     = (const float*)d_in[4];
    const float* rb1     = (const float*)d_in[5];
    const float* rW2     = (const float*)d_in[6];
    const float* rb2     = (const float*)d_in[7];
    const float* rW3     = (const float*)d_in[8];
    const float* rb3     = (const float*)d_in[9];
    const float* oW1     = (const float*)d_in[10];
    const float* ob1     = (const float*)d_in[11];
    const float* oW2     = (const float*)d_in[12];
    const float* ob2     = (const float*)d_in[13];

    char* ws = (char*)d_ws;
    int*            snd_idx = (int*)(ws + 0);               // 128 KiB
    int*            rcv_idx = (int*)(ws + (128 << 10));     // 128 KiB
    float*          eff_rcv = (float*)(ws + (256 << 10));   //  32 KiB
    unsigned short* w2t     = (unsigned short*)(ws + (288 << 10)); // 50 KiB
    float*          b2p     = (float*)(ws + (344 << 10));   //  640 B
    float*          w3p     = (float*)(ws + (345 << 10));   //  640 B

    // 1) scan one-hot matrices + prep bf16 weights + zero eff_rcv (HBM-bound)
    scan_prep_kernel<<<4096, 256, 0, stream>>>(
        S, R, rW2, rb2, rW3, snd_idx, rcv_idx, w2t, b2p, w3p, eff_rcv);

    // 2) edge MLP pass 0 (MFMA layer 2) -> scatter-add effects
    edge0_kernel<<<(BB * EE) / 64, 512, 0, stream>>>(
        objects, snd_idx, rcv_idx, rel, rW1, rb1, w2t, b2p, w3p, rb3, eff_rcv);

    // 3) fused object MLP + final relational pass (MFMA) -> edge weights
    edge1_kernel<<<(BB * EE) / 64, 512, 0, stream>>>(
        objects, eff_rcv, snd_idx, rcv_idx, rel, oW1, ob1, oW2, ob2,
        rW1, rb1, w2t, b2p, w3p, rb3, (float*)d_out);
}